// Round 11
// baseline (1703.677 us; speedup 1.0000x reference)
//
#include <hip/hip_runtime.h>
#include <cstdint>
#include <cstddef>

// Problem constants
#define BATCH   8
#define KPTS    8192
#define NPT     1024
#define NSAMP   16
#define RAD2    0.09f
#define NWORKER 248
#define HB      136
#define SMEM_BYTES 98432   // = max(FPS: 3*32768+128, Tail: ~90.9 KB)

typedef float f32x2 __attribute__((ext_vector_type(2)));
typedef float f32x4 __attribute__((ext_vector_type(4)));
typedef short s16x4 __attribute__((ext_vector_type(4)));
typedef short s16x8 __attribute__((ext_vector_type(8)));

__device__ __forceinline__ unsigned short f2bf(float x) {
    unsigned u = __float_as_uint(x);
    return (unsigned short)((u + 0x7fffu + ((u >> 16) & 1u)) >> 16);
}

template <int CTRL>
__device__ __forceinline__ unsigned long long dpp_max_step(unsigned long long v) {
    unsigned int lo = (unsigned int)v, hi = (unsigned int)(v >> 32);
    unsigned int lo2 = (unsigned int)__builtin_amdgcn_update_dpp(0, (int)lo, CTRL, 0xf, 0xf, true);
    unsigned int hi2 = (unsigned int)__builtin_amdgcn_update_dpp(0, (int)hi, CTRL, 0xf, 0xf, true);
    unsigned long long o = ((unsigned long long)hi2 << 32) | lo2;
    return o > v ? o : v;
}

// Tail-phase shared-memory view (~90.9 KB)
struct __align__(16) TailSm {
    unsigned short hbf[128 * HB];   // 34816 B
    unsigned short Wsh[128 * HB];   // 34816 B
    float gx[128], gy[128], gz[128];
    int   pidx[128];
    float s0[128], t0[128], wxs[128], wys[128], wzs[128];
    float s1[128], t1[128], s2[128], t2[128];
    float hs1[128], ht1[128], hs2[128], ht2[128];
    float ms[54];
    float featL[8][128], n1[8][128], n2[8][128];
};

// ---------------------------------------------------------------------------
// Persistent mega-kernel, grid=256 x 512 threads, ~98 KB LDS -> exactly
// 1 block/CU, 256 blocks <= 256 CUs => ALL blocks co-resident under any
// dispatch order (pigeonhole) => spin-waits are deadlock-free.
// Blocks 0..7: FPS (R6-verified chain) + progress release-signal every 64 it.
// Blocks 8..255: workers — f0 tiles, then gated 8-query tail items
// (ballq + MFMA MLP + head), overlapping the FPS shadow.
// ---------------------------------------------------------------------------
__global__ __launch_bounds__(512, 1) void mega_kernel(
    const float* __restrict__ xyz, float* __restrict__ new_xyz,
    const float* __restrict__ feats, float* __restrict__ f0out,
    const float* __restrict__ w0,
    const float* __restrict__ g0, const float* __restrict__ b0,
    const float* __restrict__ m0, const float* __restrict__ v0,
    const float* __restrict__ w1,
    const float* __restrict__ g1, const float* __restrict__ b1a,
    const float* __restrict__ m1, const float* __restrict__ v1,
    const float* __restrict__ w2,
    const float* __restrict__ g2, const float* __restrict__ b2a,
    const float* __restrict__ m2, const float* __restrict__ v2,
    const float* __restrict__ c1w, const float* __restrict__ c1b,
    const float* __restrict__ c2w, const float* __restrict__ c2b,
    const float* __restrict__ c3w, const float* __restrict__ c3b,
    const float* __restrict__ bg1, const float* __restrict__ bb1,
    const float* __restrict__ bm1, const float* __restrict__ bv1,
    const float* __restrict__ bg2, const float* __restrict__ bb2,
    const float* __restrict__ bm2, const float* __restrict__ bv2,
    const float* __restrict__ msz,
    int* __restrict__ prog, int* __restrict__ f0ctr,
    float* __restrict__ out) {

    __shared__ __align__(16) char smem_raw[SMEM_BYTES];
    const int tid = threadIdx.x;

    if (blockIdx.x < 8) {
        // ============================ FPS ============================
        {
#pragma clang fp contract(off)
            float* xs = (float*)smem_raw;
            float* ys = xs + KPTS;
            float* zs = ys + KPTS;
            unsigned long long* wslot = (unsigned long long*)(zs + KPTS); // [2][8]

            const int b = blockIdx.x;
            const float* xb = xyz + (size_t)b * KPTS * 3;

            for (int i = tid; i < KPTS; i += 512) {
                xs[i] = xb[i * 3 + 0];
                ys[i] = xb[i * 3 + 1];
                zs[i] = xb[i * 3 + 2];
            }
            __syncthreads();

            const int base = tid << 4;  // 16 points per thread
            f32x2 px[8], py[8], pz[8], dmn[8];
#pragma unroll
            for (int j = 0; j < 8; ++j) {
                int i0 = base + (j << 1);
                px[j] = (f32x2){xs[i0], xs[i0 + 1]};
                py[j] = (f32x2){ys[i0], ys[i0 + 1]};
                pz[j] = (f32x2){zs[i0], zs[i0 + 1]};
                dmn[j] = (f32x2){1e10f, 1e10f};
            }

            int far = 0;
            for (int it = 0; it < NPT; ++it) {
                const float cx = xs[far], cy = ys[far], cz = zs[far];
                if (tid == 0) {
                    float* o = new_xyz + ((size_t)b * NPT + it) * 3;
                    o[0] = cx; o[1] = cy; o[2] = cz;   // measured free (R5)
                    if ((it & 63) == 63) {
                        __threadfence();
                        __hip_atomic_store(&prog[b], it + 1, __ATOMIC_RELEASE,
                                           __HIP_MEMORY_SCOPE_AGENT);
                    }
                }
                const f32x2 cx2 = (f32x2){cx, cx};
                const f32x2 cy2 = (f32x2){cy, cy};
                const f32x2 cz2 = (f32x2){cz, cz};

                f32x2 mm = (f32x2){-1.0f, -1.0f};
#pragma unroll
                for (int j = 0; j < 8; ++j) {
                    f32x2 dx = px[j] - cx2;
                    f32x2 dy = py[j] - cy2;
                    f32x2 dz = pz[j] - cz2;
                    f32x2 d  = (dx * dx + dy * dy) + dz * dz;
                    f32x2 nd = __builtin_elementwise_min(dmn[j], d);
                    dmn[j] = nd;
                    mm = __builtin_elementwise_max(mm, nd);
                }
                float lmax = fmaxf(mm.x, mm.y);

                int ci = 0x7fffffff;
#pragma unroll
                for (int j = 0; j < 8; ++j) {
                    if (dmn[j].x == lmax) ci = min(ci, base + (j << 1));
                    if (dmn[j].y == lmax) ci = min(ci, base + (j << 1) + 1);
                }

                unsigned long long pk =
                    ((unsigned long long)__float_as_uint(lmax) << 32) | (unsigned)(8191 - ci);

                pk = dpp_max_step<0x111>(pk);
                pk = dpp_max_step<0x112>(pk);
                pk = dpp_max_step<0x114>(pk);
                pk = dpp_max_step<0x118>(pk);
                pk = dpp_max_step<0x142>(pk);
                pk = dpp_max_step<0x143>(pk);

                if ((tid & 63) == 63) wslot[(it & 1) * 8 + (tid >> 6)] = pk;
                __syncthreads();

                const unsigned long long* ws = &wslot[(it & 1) * 8];
                ulonglong2 s01 = *(const ulonglong2*)&ws[0];
                ulonglong2 s23 = *(const ulonglong2*)&ws[2];
                ulonglong2 s45 = *(const ulonglong2*)&ws[4];
                ulonglong2 s67 = *(const ulonglong2*)&ws[6];
                unsigned long long g = s01.x;
                if (s01.y > g) g = s01.y;
                if (s23.x > g) g = s23.x;
                if (s23.y > g) g = s23.y;
                if (s45.x > g) g = s45.x;
                if (s45.y > g) g = s45.y;
                if (s67.x > g) g = s67.x;
                if (s67.y > g) g = s67.y;
                far = 8191 - (int)(unsigned)(g & 0xffffffffull);
            }
            // final signal (it=1023 signaled prog=1024 already at (1023&63)==63)
        }
        return;
    }

    // ============================ WORKER ============================
    const int wkr = blockIdx.x - 8;

    // ---- Phase W1: F0 tiles (R6 512-thread tile code)
    {
        float* As = (float*)smem_raw;          // 16*128
        float* Bs = As + 16 * 128;             // 16*130
        for (int t = wkr; t < 512; t += NWORKER) {
            const int b  = t >> 6;
            const int p0 = (t & 63) << 7;
            const int rb = (tid >> 4) << 2;
            const int ob = tid & 15;
            const float* fb = feats + (size_t)b * 256 * KPTS;

            float acc[4][8];
#pragma unroll
            for (int r = 0; r < 4; ++r)
#pragma unroll
                for (int c = 0; c < 8; ++c) acc[r][c] = 0.f;

            for (int k0 = 0; k0 < 256; k0 += 16) {
#pragma unroll
                for (int i = 0; i < 4; ++i) {
                    int e = tid + (i << 9);
                    int kk = e >> 7, pc = e & 127;
                    As[kk * 128 + pc] = fb[(size_t)(k0 + kk) * KPTS + p0 + pc];
                }
#pragma unroll
                for (int i = 0; i < 4; ++i) {
                    int e = tid + (i << 9);
                    int o = e >> 4, kk = e & 15;
                    Bs[kk * 130 + o] = w0[o * 259 + 3 + k0 + kk];
                }
                __syncthreads();
#pragma unroll
                for (int kk = 0; kk < 16; ++kk) {
                    float a[4], wvv[8];
#pragma unroll
                    for (int r = 0; r < 4; ++r) a[r] = As[kk * 128 + rb + r];
#pragma unroll
                    for (int c = 0; c < 8; ++c) wvv[c] = Bs[kk * 130 + ob + (c << 4)];
#pragma unroll
                    for (int r = 0; r < 4; ++r)
#pragma unroll
                        for (int c = 0; c < 8; ++c) acc[r][c] = fmaf(a[r], wvv[c], acc[r][c]);
                }
                __syncthreads();
            }
#pragma unroll
            for (int r = 0; r < 4; ++r) {
                float* outp = f0out + ((size_t)b * KPTS + p0 + rb + r) * 128 + ob;
#pragma unroll
                for (int c = 0; c < 8; ++c) outp[c << 4] = acc[r][c];
            }
            __syncthreads();   // stores consumed; safe to restage As/Bs
        }
    }
    // publish our F0 tiles; wait for all workers' tiles
    __threadfence();
    __syncthreads();
    if (tid == 0) atomicAdd(f0ctr, 1);
    if (tid == 0) {
        int spins = 0;
        while (__hip_atomic_load(f0ctr, __ATOMIC_ACQUIRE, __HIP_MEMORY_SCOPE_AGENT) < NWORKER) {
            __builtin_amdgcn_s_sleep(64);
            if (++spins > 300000) break;
        }
    }
    __syncthreads();
    __threadfence();

    // ---- Load per-block-constant params once
    TailSm* ts = (TailSm*)smem_raw;
    if (tid < 128) {
        float sc = g0[tid] / sqrtf(v0[tid] + 1e-5f);
        ts->s0[tid] = sc; ts->t0[tid] = b0[tid] - m0[tid] * sc;
        sc = g1[tid] / sqrtf(v1[tid] + 1e-5f);
        ts->s1[tid] = sc; ts->t1[tid] = b1a[tid] - m1[tid] * sc;
        sc = g2[tid] / sqrtf(v2[tid] + 1e-5f);
        ts->s2[tid] = sc; ts->t2[tid] = b2a[tid] - m2[tid] * sc;
        sc = bg1[tid] / sqrtf(bv1[tid] + 1e-5f);
        ts->hs1[tid] = sc; ts->ht1[tid] = bb1[tid] - bm1[tid] * sc;
        sc = bg2[tid] / sqrtf(bv2[tid] + 1e-5f);
        ts->hs2[tid] = sc; ts->ht2[tid] = bb2[tid] - bm2[tid] * sc;
        ts->wxs[tid] = w0[tid * 259 + 0];
        ts->wys[tid] = w0[tid * 259 + 1];
        ts->wzs[tid] = w0[tid * 259 + 2];
    }
    if (tid < 54) ts->ms[tid] = msz[tid];
    __syncthreads();

    const int w    = tid >> 6;        // wave 0..7 = query within item
    const int lane = tid & 63;
    const int l15  = lane & 15;
    const int quad = lane >> 4;
    const int wrow = w << 4;

    // ---- Phase W2: gated tail items (8 queries each)
    for (int item = wkr; item < 1024; item += NWORKER) {
        const int q0 = item << 3;
        const int b  = q0 >> 10;
        const int need = (q0 & 1023) + 8;

        if (tid == 0) {
            int spins = 0;
            while (__hip_atomic_load(&prog[b], __ATOMIC_ACQUIRE,
                                     __HIP_MEMORY_SCOPE_AGENT) < need) {
                __builtin_amdgcn_s_sleep(64);
                if (++spins > 300000) break;
            }
        }
        __syncthreads();
        __threadfence();

        // -- ballq: wave w handles query q0+w
        {
            const int q = q0 + w;
            const float* xb = xyz + (size_t)b * KPTS * 3;
            const float qx = new_xyz[q * 3 + 0];
            const float qy = new_xyz[q * 3 + 1];
            const float qz = new_xyz[q * 3 + 2];
            int* op = &ts->pidx[w * NSAMP];

            int total = 0;
            int first_p = 0;
            for (int c = 0; c < KPTS / 64; ++c) {
                int p = (c << 6) + lane;
                float pxv = xb[p * 3 + 0], pyv = xb[p * 3 + 1], pzv = xb[p * 3 + 2];
                float dx = __fsub_rn(qx, pxv), dy = __fsub_rn(qy, pyv), dz = __fsub_rn(qz, pzv);
                float d2 = __fadd_rn(__fadd_rn(__fmul_rn(dx, dx), __fmul_rn(dy, dy)),
                                     __fmul_rn(dz, dz));
                bool pred = d2 < RAD2;
                unsigned long long mask = __ballot(pred);
                if (total == 0 && mask != 0ull) first_p = (c << 6) + (int)__builtin_ctzll(mask);
                if (pred) {
                    int rank = (int)__popcll(mask & ((1ull << lane) - 1ull));
                    int slot = total + rank;
                    if (slot < NSAMP) op[slot] = p;
                }
                total += (int)__popcll(mask);
                if (total >= NSAMP) break;
            }
            if (total < NSAMP && lane >= total && lane < NSAMP) op[lane] = first_p;
        }
        __syncthreads();

        // -- grouped xyz
        if (tid < 128) {
            int p = ts->pidx[tid];
            int q = q0 + (tid >> 4);
            const float* pp = xyz + ((size_t)b * KPTS + p) * 3;
            const float* nq = new_xyz + (size_t)q * 3;
            ts->gx[tid] = (pp[0] - nq[0]) / 0.3f;
            ts->gy[tid] = (pp[1] - nq[1]) / 0.3f;
            ts->gz[tid] = (pp[2] - nq[2]) / 0.3f;
        }
        __syncthreads();

        // -- gather F0 + BN0 + ReLU -> hbf (bf16); stage w1
#pragma unroll 2
        for (int i = 0; i < 8; ++i) {
            int e = tid + (i << 9);
            int row = e >> 5, o = (e & 31) << 2;
            int p = ts->pidx[row];
            float4 v4 = *(const float4*)(f0out + ((size_t)b * KPTS + p) * 128 + o);
            float gxr = ts->gx[row], gyr = ts->gy[row], gzr = ts->gz[row];
            float r0 = fmaf(ts->wzs[o + 0], gzr, fmaf(ts->wys[o + 0], gyr, fmaf(ts->wxs[o + 0], gxr, v4.x)));
            float r1 = fmaf(ts->wzs[o + 1], gzr, fmaf(ts->wys[o + 1], gyr, fmaf(ts->wxs[o + 1], gxr, v4.y)));
            float r2 = fmaf(ts->wzs[o + 2], gzr, fmaf(ts->wys[o + 2], gyr, fmaf(ts->wxs[o + 2], gxr, v4.z)));
            float r3 = fmaf(ts->wzs[o + 3], gzr, fmaf(ts->wys[o + 3], gyr, fmaf(ts->wxs[o + 3], gxr, v4.w)));
            s16x4 c4;
            c4.x = (short)f2bf(fmaxf(fmaf(r0, ts->s0[o + 0], ts->t0[o + 0]), 0.f));
            c4.y = (short)f2bf(fmaxf(fmaf(r1, ts->s0[o + 1], ts->t0[o + 1]), 0.f));
            c4.z = (short)f2bf(fmaxf(fmaf(r2, ts->s0[o + 2], ts->t0[o + 2]), 0.f));
            c4.w = (short)f2bf(fmaxf(fmaf(r3, ts->s0[o + 3], ts->t0[o + 3]), 0.f));
            *(s16x4*)&ts->hbf[row * HB + o] = c4;
        }
#pragma unroll 2
        for (int i = 0; i < 8; ++i) {
            int e = tid + (i << 9);
            int o = e >> 5;
            int kt = (e & 31) << 2;
            float4 w4 = *(const float4*)(w1 + o * 128 + kt);
            s16x4 c4 = { (short)f2bf(w4.x), (short)f2bf(w4.y),
                         (short)f2bf(w4.z), (short)f2bf(w4.w) };
            *(s16x4*)&ts->Wsh[o * HB + kt] = c4;
        }
        __syncthreads();

        // -- Layer 1 MFMA
        f32x4 acc[8];
#pragma unroll
        for (int t = 0; t < 8; ++t) acc[t] = (f32x4){0.f, 0.f, 0.f, 0.f};
#pragma unroll
        for (int k0 = 0; k0 < 128; k0 += 32) {
            s16x8 a = *(const s16x8*)&ts->hbf[(wrow + l15) * HB + k0 + (quad << 3)];
#pragma unroll
            for (int t = 0; t < 8; ++t) {
                s16x8 bf = *(const s16x8*)&ts->Wsh[((t << 4) + l15) * HB + k0 + (quad << 3)];
                acc[t] = __builtin_amdgcn_mfma_f32_16x16x32_bf16(a, bf, acc[t], 0, 0, 0);
            }
        }
        __syncthreads();

        // -- writeback L1 (own rows) + stage w2
#pragma unroll
        for (int t = 0; t < 8; ++t) {
            int o = (t << 4) + l15;
            float ss = ts->s1[o], tt = ts->t1[o];
#pragma unroll
            for (int r = 0; r < 4; ++r) {
                float v = fmaxf(fmaf(acc[t][r], ss, tt), 0.f);
                ts->hbf[(wrow + (quad << 2) + r) * HB + o] = f2bf(v);
            }
        }
#pragma unroll 2
        for (int i = 0; i < 8; ++i) {
            int e = tid + (i << 9);
            int o = e >> 5;
            int kt = (e & 31) << 2;
            float4 w4 = *(const float4*)(w2 + o * 128 + kt);
            s16x4 c4 = { (short)f2bf(w4.x), (short)f2bf(w4.y),
                         (short)f2bf(w4.z), (short)f2bf(w4.w) };
            *(s16x4*)&ts->Wsh[o * HB + kt] = c4;
        }
        __syncthreads();

        // -- Layer 2 MFMA + BN2/ReLU + register maxpool -> featL
#pragma unroll
        for (int t = 0; t < 8; ++t) acc[t] = (f32x4){0.f, 0.f, 0.f, 0.f};
#pragma unroll
        for (int k0 = 0; k0 < 128; k0 += 32) {
            s16x8 a = *(const s16x8*)&ts->hbf[(wrow + l15) * HB + k0 + (quad << 3)];
#pragma unroll
            for (int t = 0; t < 8; ++t) {
                s16x8 bf = *(const s16x8*)&ts->Wsh[((t << 4) + l15) * HB + k0 + (quad << 3)];
                acc[t] = __builtin_amdgcn_mfma_f32_16x16x32_bf16(a, bf, acc[t], 0, 0, 0);
            }
        }
#pragma unroll
        for (int t = 0; t < 8; ++t) {
            int o = (t << 4) + l15;
            float ss = ts->s2[o], tt = ts->t2[o];
            float m0v = fmaxf(fmaf(acc[t][0], ss, tt), 0.f);
            float m1v = fmaxf(fmaf(acc[t][1], ss, tt), 0.f);
            float m2v = fmaxf(fmaf(acc[t][2], ss, tt), 0.f);
            float m3v = fmaxf(fmaf(acc[t][3], ss, tt), 0.f);
            float m = fmaxf(fmaxf(m0v, m1v), fmaxf(m2v, m3v));
            m = fmaxf(m, __shfl_xor(m, 16));
            m = fmaxf(m, __shfl_xor(m, 32));
            if (quad == 0) ts->featL[w][o] = m;
        }
        __syncthreads();

        // -- head: o = tid&127, grp = tid>>7 in [0,4), 2 queries per grp
        {
            const int o   = tid & 127;
            const int grp = tid >> 7;

            {
                float a[2];
                a[0] = c1b[o]; a[1] = c1b[o];
                const float* wr = c1w + o * 128;
                for (int k = 0; k < 128; k += 4) {
                    float4 w4 = *(const float4*)(wr + k);
#pragma unroll
                    for (int j = 0; j < 2; ++j) {
                        int qq = grp * 2 + j;
                        a[j] = fmaf(ts->featL[qq][k + 0], w4.x, a[j]);
                        a[j] = fmaf(ts->featL[qq][k + 1], w4.y, a[j]);
                        a[j] = fmaf(ts->featL[qq][k + 2], w4.z, a[j]);
                        a[j] = fmaf(ts->featL[qq][k + 3], w4.w, a[j]);
                    }
                }
#pragma unroll
                for (int j = 0; j < 2; ++j)
                    ts->n1[grp * 2 + j][o] = fmaxf(fmaf(a[j], ts->hs1[o], ts->ht1[o]), 0.f);
            }
            __syncthreads();
            {
                float a[2];
                a[0] = c2b[o]; a[1] = c2b[o];
                const float* wr = c2w + o * 128;
                for (int k = 0; k < 128; k += 4) {
                    float4 w4 = *(const float4*)(wr + k);
#pragma unroll
                    for (int j = 0; j < 2; ++j) {
                        int qq = grp * 2 + j;
                        a[j] = fmaf(ts->n1[qq][k + 0], w4.x, a[j]);
                        a[j] = fmaf(ts->n1[qq][k + 1], w4.y, a[j]);
                        a[j] = fmaf(ts->n1[qq][k + 2], w4.z, a[j]);
                        a[j] = fmaf(ts->n1[qq][k + 3], w4.w, a[j]);
                    }
                }
#pragma unroll
                for (int j = 0; j < 2; ++j)
                    ts->n2[grp * 2 + j][o] = fmaxf(fmaf(a[j], ts->hs2[o], ts->ht2[o]), 0.f);
            }
            __syncthreads();
            if (o < 97) {
                float a[2];
                a[0] = c3b[o]; a[1] = c3b[o];
                const float* wr = c3w + o * 128;
                for (int k = 0; k < 128; k += 4) {
                    float4 w4 = *(const float4*)(wr + k);
#pragma unroll
                    for (int j = 0; j < 2; ++j) {
                        int qq = grp * 2 + j;
                        a[j] = fmaf(ts->n2[qq][k + 0], w4.x, a[j]);
                        a[j] = fmaf(ts->n2[qq][k + 1], w4.y, a[j]);
                        a[j] = fmaf(ts->n2[qq][k + 2], w4.z, a[j]);
                        a[j] = fmaf(ts->n2[qq][k + 3], w4.w, a[j]);
                    }
                }
#pragma unroll
                for (int j = 0; j < 2; ++j) {
                    int q = q0 + grp * 2 + j;
                    float v = a[j];
                    if (o >= 2 && o < 5) v += new_xyz[(size_t)q * 3 + (o - 2)];
                    else if (o == 6) v *= 3.14159265358979323846f;  // * (pi/NH)
                    else if (o >= 25 && o < 79) v *= ts->ms[o - 25]; // sr * mean_size
                    out[(size_t)q * 97 + o] = v;
                }
            }
        }
        __syncthreads();   // LDS reused by next item
    }
}

// ---------------------------------------------------------------------------
extern "C" void kernel_launch(void* const* d_in, const int* in_sizes, int n_in,
                              void* d_out, int out_size, void* d_ws, size_t ws_size,
                              hipStream_t stream) {
    const float* xyz      = (const float*)d_in[0];
    const float* features = (const float*)d_in[1];
    const float* w0  = (const float*)d_in[2];
    const float* g0  = (const float*)d_in[3];
    const float* b0  = (const float*)d_in[4];
    const float* m0  = (const float*)d_in[5];
    const float* v0  = (const float*)d_in[6];
    const float* w1  = (const float*)d_in[7];
    const float* g1  = (const float*)d_in[8];
    const float* b1  = (const float*)d_in[9];
    const float* m1  = (const float*)d_in[10];
    const float* v1  = (const float*)d_in[11];
    const float* w2  = (const float*)d_in[12];
    const float* g2  = (const float*)d_in[13];
    const float* b2  = (const float*)d_in[14];
    const float* m2  = (const float*)d_in[15];
    const float* v2  = (const float*)d_in[16];
    const float* c1w = (const float*)d_in[17];
    const float* c1b = (const float*)d_in[18];
    const float* c2w = (const float*)d_in[19];
    const float* c2b = (const float*)d_in[20];
    const float* c3w = (const float*)d_in[21];
    const float* c3b = (const float*)d_in[22];
    const float* bg1 = (const float*)d_in[23];
    const float* bb1 = (const float*)d_in[24];
    const float* bm1 = (const float*)d_in[25];
    const float* bv1 = (const float*)d_in[26];
    const float* bg2 = (const float*)d_in[27];
    const float* bb2 = (const float*)d_in[28];
    const float* bm2 = (const float*)d_in[29];
    const float* bv2 = (const float*)d_in[30];
    const float* msz = (const float*)d_in[31];

    // Workspace: F0 (33.55 MB) + nxyz (96 KB) + prog[8]/f0ctr (64 B)
    float* F0   = (float*)d_ws;
    float* nxyz = F0 + (size_t)BATCH * KPTS * 128;
    int*   prog = (int*)(nxyz + (size_t)BATCH * NPT * 3);
    int*   f0ctr = prog + 8;
    float* outp = (float*)d_out;

    hipMemsetAsync(prog, 0, 64, stream);   // prog[8] + f0ctr (ws is 0xAA-poisoned)
    mega_kernel<<<256, 512, 0, stream>>>(
        xyz, nxyz, features, F0, w0,
        g0, b0, m0, v0, w1, g1, b1, m1, v1, w2, g2, b2, m2, v2,
        c1w, c1b, c2w, c2b, c3w, c3b,
        bg1, bb1, bm1, bv1, bg2, bb2, bm2, bv2, msz,
        prog, f0ctr, outp);
}